// Round 4
// baseline (462.335 us; speedup 1.0000x reference)
//
#include <hip/hip_runtime.h>
#include <hip/hip_bf16.h>

// ---------------- constants ----------------
#define T_TOK   4096
#define HID     1024
#define INTER   4096
#define NEXP    8
#define MAXT    72          // max total row-tiles: (8192 + 8*127)/128 = 72
#define MAXSLOT 9216        // MAXT * 128
#define TPB_TOK 16          // tokens per gating block

typedef __attribute__((ext_vector_type(8))) short s16x8;
typedef __attribute__((ext_vector_type(4))) float f32x4;

__device__ __forceinline__ void load_lds16(const void* g, void* l) {
    __builtin_amdgcn_global_load_lds(
        (const __attribute__((address_space(1))) void*)g,
        (__attribute__((address_space(3))) void*)l, 16, 0, 0);
}

__device__ __forceinline__ float gelu_tanh(float v) {
    float c = 0.7978845608028654f;
    float u = v + 0.044715f * v * v * v;
    return 0.5f * v * (1.0f + tanhf(c * u));
}

// ---------------- transpose+convert weights: in [E][R][C] f32 -> out [E][C][R] bf16 ----------------
__global__ void transpose_bf16_kernel(const float* __restrict__ in, __hip_bfloat16* __restrict__ out,
                                      int R, int C) {
    __shared__ float tile[32][33];
    size_t eoff = (size_t)blockIdx.z * R * C;
    int c0 = blockIdx.x * 32, r0 = blockIdx.y * 32;
    int tx = threadIdx.x & 31, ty = threadIdx.x >> 5;   // 256 threads: 32 x 8
    #pragma unroll
    for (int i = 0; i < 32; i += 8)
        tile[ty + i][tx] = in[eoff + (size_t)(r0 + ty + i) * C + c0 + tx];
    __syncthreads();
    #pragma unroll
    for (int i = 0; i < 32; i += 8)
        out[eoff + (size_t)(c0 + ty + i) * R + r0 + tx] = __float2bfloat16(tile[tx][ty + i]);
}

// ---------------- gating: 16 tokens per block, block-aggregated atomics ----------------
__global__ void gating_kernel(const float* __restrict__ x, const float* __restrict__ Wg,
                              __hip_bfloat16* __restrict__ xb,
                              float* __restrict__ combine, int* __restrict__ counts,
                              float* __restrict__ prob_sums, int* __restrict__ idxcap) {
    __shared__ float s_ps[NEXP];
    __shared__ int   s_cnt[NEXP];
    __shared__ int   s_base[NEXP];
    __shared__ int   s_ei[TPB_TOK][2];
    __shared__ int   s_rk[TPB_TOK][2];

    int tid = threadIdx.x, wv = tid >> 6, ln = tid & 63;
    if (tid < NEXP) { s_ps[tid] = 0.f; s_cnt[tid] = 0; }
    __syncthreads();

    int t0 = blockIdx.x * TPB_TOK;
    for (int sub = 0; sub < 4; ++sub) {
        int tl = wv * 4 + sub;          // 0..15 local token
        int t = t0 + tl;
        const float* xr = x + (size_t)t * HID + ln * 16;
        float4 xv[4];
        #pragma unroll
        for (int i = 0; i < 4; ++i) xv[i] = *(const float4*)(xr + i * 4);

        __hip_bfloat16 row[16];
        #pragma unroll
        for (int i = 0; i < 4; ++i) {
            row[i * 4 + 0] = __float2bfloat16(xv[i].x);
            row[i * 4 + 1] = __float2bfloat16(xv[i].y);
            row[i * 4 + 2] = __float2bfloat16(xv[i].z);
            row[i * 4 + 3] = __float2bfloat16(xv[i].w);
        }
        __hip_bfloat16* xbr = xb + (size_t)t * HID + ln * 16;
        *(s16x8*)(xbr)     = *(s16x8*)&row[0];
        *(s16x8*)(xbr + 8) = *(s16x8*)&row[8];

        float acc[NEXP] = {0,0,0,0,0,0,0,0};
        #pragma unroll
        for (int i = 0; i < 4; ++i) {
            float xs[4] = {xv[i].x, xv[i].y, xv[i].z, xv[i].w};
            #pragma unroll
            for (int j = 0; j < 4; ++j) {
                int k = ln * 16 + i * 4 + j;
                float4 wa = *(const float4*)(Wg + (size_t)k * 8);
                float4 wb = *(const float4*)(Wg + (size_t)k * 8 + 4);
                acc[0] += xs[j] * wa.x; acc[1] += xs[j] * wa.y;
                acc[2] += xs[j] * wa.z; acc[3] += xs[j] * wa.w;
                acc[4] += xs[j] * wb.x; acc[5] += xs[j] * wb.y;
                acc[6] += xs[j] * wb.z; acc[7] += xs[j] * wb.w;
            }
        }
        #pragma unroll
        for (int e = 0; e < NEXP; ++e)
            #pragma unroll
            for (int off = 32; off >= 1; off >>= 1)
                acc[e] += __shfl_xor(acc[e], off);

        float m = acc[0];
        #pragma unroll
        for (int e = 1; e < NEXP; ++e) m = fmaxf(m, acc[e]);
        float p[NEXP], s = 0.f;
        #pragma unroll
        for (int e = 0; e < NEXP; ++e) { p[e] = __expf(acc[e] - m); s += p[e]; }
        float inv = 1.0f / s;
        #pragma unroll
        for (int e = 0; e < NEXP; ++e) p[e] *= inv;

        int i0 = 0;
        #pragma unroll
        for (int e = 1; e < NEXP; ++e) if (p[e] > p[i0]) i0 = e;
        int i1 = (i0 == 0) ? 1 : 0;
        #pragma unroll
        for (int e = 0; e < NEXP; ++e) if (e != i0 && p[e] > p[i1]) i1 = e;
        float gs = p[i0] + p[i1];
        float g0 = p[i0] / gs, g1 = p[i1] / gs;

        if (ln == 0) {
            float rowc[NEXP] = {0,0,0,0,0,0,0,0};
            rowc[i0] = g0; rowc[i1] = g1;
            float4* cr = (float4*)(combine + (size_t)t * NEXP);
            cr[0] = make_float4(rowc[0], rowc[1], rowc[2], rowc[3]);
            cr[1] = make_float4(rowc[4], rowc[5], rowc[6], rowc[7]);
            #pragma unroll
            for (int e = 0; e < NEXP; ++e) atomicAdd(&s_ps[e], p[e]);
            int r0 = atomicAdd(&s_cnt[i0], 1);
            int r1 = atomicAdd(&s_cnt[i1], 1);
            s_ei[tl][0] = i0; s_rk[tl][0] = r0;
            s_ei[tl][1] = i1; s_rk[tl][1] = r1;
        }
    }
    __syncthreads();
    if (tid < NEXP) {
        s_base[tid] = atomicAdd(&counts[tid], s_cnt[tid]);
        atomicAdd(&prob_sums[tid], s_ps[tid]);
    }
    __syncthreads();
    if (tid < TPB_TOK * 2) {
        int tl = tid >> 1, k = tid & 1;
        int e = s_ei[tl][k];
        idxcap[e * T_TOK + s_base[e] + s_rk[tl][k]] = t0 + tl;
    }
}

// ---------------- plan: offsets, tile table, aux loss (1 thread) ----------------
__global__ void plan_kernel(const int* __restrict__ counts, const float* __restrict__ prob_sums,
                            int* __restrict__ offs, int* __restrict__ tile_e,
                            int* __restrict__ tile_s0, int* __restrict__ tile_nv,
                            int* __restrict__ ntiles, float* __restrict__ aux_out) {
    int tt = 0, o = 0;
    for (int e = 0; e < NEXP; ++e) {
        offs[e] = o;
        int n = counts[e];
        int nt = (n + 127) >> 7;
        for (int r = 0; r < nt; ++r) {
            tile_e[tt] = e;
            tile_s0[tt] = o + r * 128;
            int nv = n - r * 128; if (nv > 128) nv = 128;
            tile_nv[tt] = nv;
            ++tt;
        }
        o += nt * 128;
    }
    *ntiles = tt;
    float aux = 0.f;
    for (int e = 0; e < NEXP; ++e)
        aux += ((float)counts[e] / (float)(T_TOK * 2)) * (prob_sums[e] / (float)T_TOK);
    aux_out[0] = (float)NEXP * aux * 0.01f;
}

// ---------------- compact token list ----------------
__global__ void compact_kernel(const int* __restrict__ counts, const int* __restrict__ offs,
                               const int* __restrict__ tile_e, const int* __restrict__ tile_s0,
                               const int* __restrict__ ntiles,
                               const int* __restrict__ idxcap, int* __restrict__ idxc) {
    int tt = blockIdx.x;
    if (tt >= *ntiles) return;
    int e = tile_e[tt];
    int slot = tile_s0[tt] + threadIdx.x;
    int i = slot - offs[e];
    int n = counts[e];
    idxc[slot] = (i < n) ? idxcap[e * T_TOK + i] : 0;
}

// ============ GEMM template pieces ============
// LDS tile [128][64] bf16 (128B rows), XOR-swizzled: 16B-slot s of row r holds
// global slot s^(r&7). global_load_lds dest stays linear; source is pre-swizzled.

// ---------------- GEMM1: h[slot] = gelu(x[tok] @ w1[e] + b1[e]) ----------------
__global__ __launch_bounds__(256, 2)
void gemm1_kernel(const __hip_bfloat16* __restrict__ xb,    // [T][H]
                  const __hip_bfloat16* __restrict__ w1b,   // [E][INTER][H]  (K-major)
                  const float* __restrict__ b1,             // [E][INTER]
                  const int* __restrict__ idxc,
                  const int* __restrict__ tile_e, const int* __restrict__ tile_s0,
                  const int* __restrict__ ntiles,
                  __hip_bfloat16* __restrict__ h)           // [MAXSLOT][INTER]
{
    const int NWG = MAXT * (INTER / 128);                   // 2304, %8==0
    int bid = blockIdx.x;
    int w = (bid & 7) * (NWG / 8) + (bid >> 3);             // XCD-chunked
    int tt = w >> 5;                                        // n0-fast
    int n0 = (w & 31) * 128;
    if (tt >= *ntiles) return;
    int e = tile_e[tt];
    int slot0 = tile_s0[tt];

    __shared__ __hip_bfloat16 As[2][128][64];
    __shared__ __hip_bfloat16 Bs[2][128][64];
    __shared__ int s_idx[128];

    int tid = threadIdx.x, wv = tid >> 6, ln = tid & 63;
    if (tid < 128) s_idx[tid] = idxc[slot0 + tid];
    __syncthreads();

    int swz = ((ln & 7) ^ (ln >> 3)) * 8;                   // pre-swizzled k-offset (elems)
    const __hip_bfloat16* srcA[4];
    const __hip_bfloat16* srcB[4];
    const __hip_bfloat16* wbase = w1b + (size_t)e * INTER * HID;
    #pragma unroll
    for (int j = 0; j < 4; ++j) {
        int r = wv * 32 + j * 8 + (ln >> 3);
        srcA[j] = xb + (size_t)s_idx[r] * HID + swz;
        srcB[j] = wbase + (size_t)(n0 + r) * HID + swz;
    }

    f32x4 acc[4][4] = {};
    int wr = wv >> 1, wc = wv & 1, lr = ln & 15;

    auto STAGE = [&](int b, int kt) {
        #pragma unroll
        for (int j = 0; j < 4; ++j) {
            load_lds16(srcA[j] + kt, (void*)&As[b][wv * 32 + j * 8][0]);
            load_lds16(srcB[j] + kt, (void*)&Bs[b][wv * 32 + j * 8][0]);
        }
    };
    auto COMPUTE = [&](int b) {
        #pragma unroll
        for (int kk = 0; kk < 2; ++kk) {
            int lslot = (((kk * 4) + (ln >> 4)) ^ (ln & 7)) * 16;
            s16x8 af[4], bf[4];
            #pragma unroll
            for (int m = 0; m < 4; ++m) {
                int row = wr * 64 + m * 16 + lr;
                af[m] = *(const s16x8*)((const char*)&As[b][0][0] + row * 128 + lslot);
            }
            #pragma unroll
            for (int n = 0; n < 4; ++n) {
                int row = wc * 64 + n * 16 + lr;
                bf[n] = *(const s16x8*)((const char*)&Bs[b][0][0] + row * 128 + lslot);
            }
            #pragma unroll
            for (int m = 0; m < 4; ++m)
                #pragma unroll
                for (int n = 0; n < 4; ++n)
                    acc[m][n] = __builtin_amdgcn_mfma_f32_16x16x32_bf16(af[m], bf[n], acc[m][n], 0, 0, 0);
        }
    };

    STAGE(0, 0);
    __syncthreads();
    int cur = 0;
    const int NT = HID / 64;
    for (int t = 0; t < NT; ++t) {
        if (t + 1 < NT) STAGE(cur ^ 1, (t + 1) * 64);
        COMPUTE(cur);
        __syncthreads();
        cur ^= 1;
    }

    const float* b1e = b1 + (size_t)e * INTER;
    int rq = (ln >> 4) * 4;
    #pragma unroll
    for (int m = 0; m < 4; ++m) {
        #pragma unroll
        for (int r = 0; r < 4; ++r) {
            int row = wr * 64 + m * 16 + rq + r;
            size_t hrow = (size_t)(slot0 + row) * INTER;
            #pragma unroll
            for (int n = 0; n < 4; ++n) {
                int col = n0 + wc * 64 + n * 16 + lr;
                float v = acc[m][n][r] + b1e[col];
                h[hrow + col] = __float2bfloat16(gelu_tanh(v));
            }
        }
    }
}

// ---------------- GEMM2: out[tok] += g * (h[slot] @ w2[e] + b2[e]) ----------------
__global__ __launch_bounds__(256, 2)
void gemm2_kernel(const __hip_bfloat16* __restrict__ h,     // [MAXSLOT][INTER]
                  const __hip_bfloat16* __restrict__ w2b,   // [E][H][INTER]  (K-major)
                  const float* __restrict__ b2,             // [E][H]
                  const float* __restrict__ combine,        // [T][E]
                  const int* __restrict__ idxc,
                  const int* __restrict__ tile_e, const int* __restrict__ tile_s0,
                  const int* __restrict__ tile_nv, const int* __restrict__ ntiles,
                  float* __restrict__ out)                  // [T][H]
{
    const int NWG = MAXT * (HID / 128);                     // 576, %8==0
    int bid = blockIdx.x;
    int w = (bid & 7) * (NWG / 8) + (bid >> 3);
    int tt = w >> 3;                                        // n0-fast (8 n-blocks)
    int n0 = (w & 7) * 128;
    if (tt >= *ntiles) return;
    int e = tile_e[tt];
    int slot0 = tile_s0[tt];

    __shared__ __hip_bfloat16 As[2][128][64];
    __shared__ __hip_bfloat16 Bs[2][128][64];
    __shared__ int s_idx[128];

    int tid = threadIdx.x, wv = tid >> 6, ln = tid & 63;
    if (tid < 128) s_idx[tid] = idxc[slot0 + tid];

    int swz = ((ln & 7) ^ (ln >> 3)) * 8;
    const __hip_bfloat16* srcA[4];
    const __hip_bfloat16* srcB[4];
    const __hip_bfloat16* wbase = w2b + (size_t)e * HID * INTER;
    #pragma unroll
    for (int j = 0; j < 4; ++j) {
        int r = wv * 32 + j * 8 + (ln >> 3);
        srcA[j] = h + (size_t)(slot0 + r) * INTER + swz;
        srcB[j] = wbase + (size_t)(n0 + r) * INTER + swz;
    }

    f32x4 acc[4][4] = {};
    int wr = wv >> 1, wc = wv & 1, lr = ln & 15;

    auto STAGE = [&](int b, int kt) {
        #pragma unroll
        for (int j = 0; j < 4; ++j) {
            load_lds16(srcA[j] + kt, (void*)&As[b][wv * 32 + j * 8][0]);
            load_lds16(srcB[j] + kt, (void*)&Bs[b][wv * 32 + j * 8][0]);
        }
    };
    auto COMPUTE = [&](int b) {
        #pragma unroll
        for (int kk = 0; kk < 2; ++kk) {
            int lslot = (((kk * 4) + (ln >> 4)) ^ (ln & 7)) * 16;
            s16x8 af[4], bf[4];
            #pragma unroll
            for (int m = 0; m < 4; ++m) {
                int row = wr * 64 + m * 16 + lr;
                af[m] = *(const s16x8*)((const char*)&As[b][0][0] + row * 128 + lslot);
            }
            #pragma unroll
            for (int n = 0; n < 4; ++n) {
                int row = wc * 64 + n * 16 + lr;
                bf[n] = *(const s16x8*)((const char*)&Bs[b][0][0] + row * 128 + lslot);
            }
            #pragma unroll
            for (int m = 0; m < 4; ++m)
                #pragma unroll
                for (int n = 0; n < 4; ++n)
                    acc[m][n] = __builtin_amdgcn_mfma_f32_16x16x32_bf16(af[m], bf[n], acc[m][n], 0, 0, 0);
        }
    };

    STAGE(0, 0);
    __syncthreads();
    int cur = 0;
    const int NT = INTER / 64;
    for (int t = 0; t < NT; ++t) {
        if (t + 1 < NT) STAGE(cur ^ 1, (t + 1) * 64);
        COMPUTE(cur);
        __syncthreads();
        cur ^= 1;
    }

    const float* b2e = b2 + (size_t)e * HID;
    int nv = tile_nv[tt];
    int rq = (ln >> 4) * 4;
    #pragma unroll
    for (int m = 0; m < 4; ++m) {
        #pragma unroll
        for (int r = 0; r < 4; ++r) {
            int row = wr * 64 + m * 16 + rq + r;
            if (row < nv) {
                int tok = s_idx[row];
                float g = combine[(size_t)tok * 8 + e];
                #pragma unroll
                for (int n = 0; n < 4; ++n) {
                    int col = n0 + wc * 64 + n * 16 + lr;
                    float v = acc[m][n][r] + b2e[col];
                    atomicAdd(&out[(size_t)tok * HID + col], g * v);
                }
            }
        }
    }
}

// ---------------- workspace layout ----------------
static const size_t OFF_XB      = 0;
static const size_t SZ_XB       = (size_t)T_TOK * HID * 2;
static const size_t OFF_W1B     = OFF_XB + SZ_XB;
static const size_t SZ_W        = (size_t)NEXP * INTER * HID * 2;
static const size_t OFF_W2B     = OFF_W1B + SZ_W;
static const size_t OFF_H       = OFF_W2B + SZ_W;
static const size_t SZ_H        = (size_t)MAXSLOT * INTER * 2;
static const size_t OFF_COMBINE = OFF_H + SZ_H;
static const size_t OFF_IDXCAP  = OFF_COMBINE + (size_t)T_TOK * 8 * 4;
static const size_t OFF_IDXC    = OFF_IDXCAP + (size_t)NEXP * T_TOK * 4;
static const size_t OFF_COUNTS  = OFF_IDXC + (size_t)MAXSLOT * 4;   // 8 ints
static const size_t OFF_PSUMS   = OFF_COUNTS + 32;                  // 8 floats
static const size_t OFF_OFFS    = OFF_PSUMS + 32;                   // 8 ints
static const size_t OFF_TILE_E  = OFF_OFFS + 64;
static const size_t OFF_TILE_S0 = OFF_TILE_E + 512;
static const size_t OFF_TILE_NV = OFF_TILE_S0 + 512;
static const size_t OFF_NTILES  = OFF_TILE_NV + 512;

extern "C" void kernel_launch(void* const* d_in, const int* in_sizes, int n_in,
                              void* d_out, int out_size, void* d_ws, size_t ws_size,
                              hipStream_t stream) {
    const float* x  = (const float*)d_in[0];
    const float* Wg = (const float*)d_in[1];
    const float* w1 = (const float*)d_in[2];
    const float* b1 = (const float*)d_in[3];
    const float* w2 = (const float*)d_in[4];
    const float* b2 = (const float*)d_in[5];
    float* out = (float*)d_out;
    char* ws = (char*)d_ws;

    __hip_bfloat16* xb   = (__hip_bfloat16*)(ws + OFF_XB);
    __hip_bfloat16* w1b  = (__hip_bfloat16*)(ws + OFF_W1B);
    __hip_bfloat16* w2b  = (__hip_bfloat16*)(ws + OFF_W2B);
    __hip_bfloat16* h    = (__hip_bfloat16*)(ws + OFF_H);
    float* combine       = (float*)(ws + OFF_COMBINE);
    int*   idxcap        = (int*)(ws + OFF_IDXCAP);
    int*   idxc          = (int*)(ws + OFF_IDXC);
    int*   counts        = (int*)(ws + OFF_COUNTS);
    float* psums         = (float*)(ws + OFF_PSUMS);
    int*   offs          = (int*)(ws + OFF_OFFS);
    int*   tile_e        = (int*)(ws + OFF_TILE_E);
    int*   tile_s0       = (int*)(ws + OFF_TILE_S0);
    int*   tile_nv       = (int*)(ws + OFF_TILE_NV);
    int*   ntiles        = (int*)(ws + OFF_NTILES);

    (void)hipMemsetAsync(out, 0, (size_t)out_size * sizeof(float), stream);
    (void)hipMemsetAsync(ws + OFF_COUNTS, 0, 64, stream);

    transpose_bf16_kernel<<<dim3(INTER / 32, HID / 32, NEXP), 256, 0, stream>>>(w1, w1b, HID, INTER);
    transpose_bf16_kernel<<<dim3(HID / 32, INTER / 32, NEXP), 256, 0, stream>>>(w2, w2b, INTER, HID);
    gating_kernel<<<T_TOK / TPB_TOK, 256, 0, stream>>>(x, Wg, xb, combine, counts, psums, idxcap);
    plan_kernel<<<1, 1, 0, stream>>>(counts, psums, offs, tile_e, tile_s0, tile_nv, ntiles,
                                     out + (size_t)T_TOK * HID);
    compact_kernel<<<MAXT, 128, 0, stream>>>(counts, offs, tile_e, tile_s0, ntiles, idxcap, idxc);
    gemm1_kernel<<<MAXT * (INTER / 128), 256, 0, stream>>>(xb, w1b, b1, idxc, tile_e, tile_s0,
                                                           ntiles, h);
    gemm2_kernel<<<MAXT * (HID / 128), 256, 0, stream>>>(h, w2b, b2, combine, idxc, tile_e,
                                                         tile_s0, tile_nv, ntiles, out);
}

// Round 5
// 382.834 us; speedup vs baseline: 1.2077x; 1.2077x over previous
//
#include <hip/hip_runtime.h>
#include <hip/hip_bf16.h>

// ---------------- constants ----------------
#define T_TOK   4096
#define HID     1024
#define INTER   4096
#define NEXP    8
#define MAXT    72          // max total row-tiles: (8192 + 8*127)/128 = 72
#define MAXSLOT 9216        // MAXT * 128
#define TPB_TOK 16          // tokens per gating block

typedef __attribute__((ext_vector_type(8))) short s16x8;
typedef __attribute__((ext_vector_type(4))) float f32x4;

__device__ __forceinline__ void load_lds16(const void* g, void* l) {
    __builtin_amdgcn_global_load_lds(
        (const __attribute__((address_space(1))) void*)g,
        (__attribute__((address_space(3))) void*)l, 16, 0, 0);
}

__device__ __forceinline__ float gelu_tanh(float v) {
    float c = 0.7978845608028654f;
    float u = v + 0.044715f * v * v * v;
    return 0.5f * v * (1.0f + tanhf(c * u));
}

// ---------------- transpose+convert weights: in [E][R][C] f32 -> out [E][C][R] bf16 ----------------
__global__ void transpose_bf16_kernel(const float* __restrict__ in, __hip_bfloat16* __restrict__ out,
                                      int R, int C) {
    __shared__ float tile[32][33];
    size_t eoff = (size_t)blockIdx.z * R * C;
    int c0 = blockIdx.x * 32, r0 = blockIdx.y * 32;
    int tx = threadIdx.x & 31, ty = threadIdx.x >> 5;   // 256 threads: 32 x 8
    #pragma unroll
    for (int i = 0; i < 32; i += 8)
        tile[ty + i][tx] = in[eoff + (size_t)(r0 + ty + i) * C + c0 + tx];
    __syncthreads();
    #pragma unroll
    for (int i = 0; i < 32; i += 8)
        out[eoff + (size_t)(c0 + ty + i) * R + r0 + tx] = __float2bfloat16(tile[tx][ty + i]);
}

// ---------------- gating: 16 tokens per block, block-aggregated atomics ----------------
__global__ void gating_kernel(const float* __restrict__ x, const float* __restrict__ Wg,
                              __hip_bfloat16* __restrict__ xb,
                              float* __restrict__ combine, int* __restrict__ counts,
                              float* __restrict__ prob_sums, int* __restrict__ idxcap) {
    __shared__ float s_ps[NEXP];
    __shared__ int   s_cnt[NEXP];
    __shared__ int   s_base[NEXP];
    __shared__ int   s_ei[TPB_TOK][2];
    __shared__ int   s_rk[TPB_TOK][2];

    int tid = threadIdx.x, wv = tid >> 6, ln = tid & 63;
    if (tid < NEXP) { s_ps[tid] = 0.f; s_cnt[tid] = 0; }
    __syncthreads();

    int t0 = blockIdx.x * TPB_TOK;
    for (int sub = 0; sub < 4; ++sub) {
        int tl = wv * 4 + sub;          // 0..15 local token
        int t = t0 + tl;
        const float* xr = x + (size_t)t * HID + ln * 16;
        float4 xv[4];
        #pragma unroll
        for (int i = 0; i < 4; ++i) xv[i] = *(const float4*)(xr + i * 4);

        __hip_bfloat16 row[16];
        #pragma unroll
        for (int i = 0; i < 4; ++i) {
            row[i * 4 + 0] = __float2bfloat16(xv[i].x);
            row[i * 4 + 1] = __float2bfloat16(xv[i].y);
            row[i * 4 + 2] = __float2bfloat16(xv[i].z);
            row[i * 4 + 3] = __float2bfloat16(xv[i].w);
        }
        __hip_bfloat16* xbr = xb + (size_t)t * HID + ln * 16;
        *(s16x8*)(xbr)     = *(s16x8*)&row[0];
        *(s16x8*)(xbr + 8) = *(s16x8*)&row[8];

        float acc[NEXP] = {0,0,0,0,0,0,0,0};
        #pragma unroll
        for (int i = 0; i < 4; ++i) {
            float xs[4] = {xv[i].x, xv[i].y, xv[i].z, xv[i].w};
            #pragma unroll
            for (int j = 0; j < 4; ++j) {
                int k = ln * 16 + i * 4 + j;
                float4 wa = *(const float4*)(Wg + (size_t)k * 8);
                float4 wb = *(const float4*)(Wg + (size_t)k * 8 + 4);
                acc[0] += xs[j] * wa.x; acc[1] += xs[j] * wa.y;
                acc[2] += xs[j] * wa.z; acc[3] += xs[j] * wa.w;
                acc[4] += xs[j] * wb.x; acc[5] += xs[j] * wb.y;
                acc[6] += xs[j] * wb.z; acc[7] += xs[j] * wb.w;
            }
        }
        #pragma unroll
        for (int e = 0; e < NEXP; ++e)
            #pragma unroll
            for (int off = 32; off >= 1; off >>= 1)
                acc[e] += __shfl_xor(acc[e], off);

        float m = acc[0];
        #pragma unroll
        for (int e = 1; e < NEXP; ++e) m = fmaxf(m, acc[e]);
        float p[NEXP], s = 0.f;
        #pragma unroll
        for (int e = 0; e < NEXP; ++e) { p[e] = __expf(acc[e] - m); s += p[e]; }
        float inv = 1.0f / s;
        #pragma unroll
        for (int e = 0; e < NEXP; ++e) p[e] *= inv;

        int i0 = 0;
        #pragma unroll
        for (int e = 1; e < NEXP; ++e) if (p[e] > p[i0]) i0 = e;
        int i1 = (i0 == 0) ? 1 : 0;
        #pragma unroll
        for (int e = 0; e < NEXP; ++e) if (e != i0 && p[e] > p[i1]) i1 = e;
        float gs = p[i0] + p[i1];
        float g0 = p[i0] / gs, g1 = p[i1] / gs;

        if (ln == 0) {
            float rowc[NEXP] = {0,0,0,0,0,0,0,0};
            rowc[i0] = g0; rowc[i1] = g1;
            float4* cr = (float4*)(combine + (size_t)t * NEXP);
            cr[0] = make_float4(rowc[0], rowc[1], rowc[2], rowc[3]);
            cr[1] = make_float4(rowc[4], rowc[5], rowc[6], rowc[7]);
            #pragma unroll
            for (int e = 0; e < NEXP; ++e) atomicAdd(&s_ps[e], p[e]);
            int r0 = atomicAdd(&s_cnt[i0], 1);
            int r1 = atomicAdd(&s_cnt[i1], 1);
            s_ei[tl][0] = i0; s_rk[tl][0] = r0;
            s_ei[tl][1] = i1; s_rk[tl][1] = r1;
        }
    }
    __syncthreads();
    if (tid < NEXP) {
        s_base[tid] = atomicAdd(&counts[tid], s_cnt[tid]);
        atomicAdd(&prob_sums[tid], s_ps[tid]);
    }
    __syncthreads();
    if (tid < TPB_TOK * 2) {
        int tl = tid >> 1, k = tid & 1;
        int e = s_ei[tl][k];
        idxcap[e * T_TOK + s_base[e] + s_rk[tl][k]] = t0 + tl;
    }
}

// ---------------- plan: offsets, tile table, aux loss (1 thread) ----------------
__global__ void plan_kernel(const int* __restrict__ counts, const float* __restrict__ prob_sums,
                            int* __restrict__ offs, int* __restrict__ tile_e,
                            int* __restrict__ tile_s0, int* __restrict__ tile_nv,
                            int* __restrict__ ntiles, float* __restrict__ aux_out) {
    int tt = 0, o = 0;
    for (int e = 0; e < NEXP; ++e) {
        offs[e] = o;
        int n = counts[e];
        int nt = (n + 127) >> 7;
        for (int r = 0; r < nt; ++r) {
            tile_e[tt] = e;
            tile_s0[tt] = o + r * 128;
            int nv = n - r * 128; if (nv > 128) nv = 128;
            tile_nv[tt] = nv;
            ++tt;
        }
        o += nt * 128;
    }
    *ntiles = tt;
    float aux = 0.f;
    for (int e = 0; e < NEXP; ++e)
        aux += ((float)counts[e] / (float)(T_TOK * 2)) * (prob_sums[e] / (float)T_TOK);
    aux_out[0] = (float)NEXP * aux * 0.01f;
}

// ---------------- compact token list ----------------
__global__ void compact_kernel(const int* __restrict__ counts, const int* __restrict__ offs,
                               const int* __restrict__ tile_e, const int* __restrict__ tile_s0,
                               const int* __restrict__ ntiles,
                               const int* __restrict__ idxcap, int* __restrict__ idxc) {
    int tt = blockIdx.x;
    if (tt >= *ntiles) return;
    int e = tile_e[tt];
    int slot = tile_s0[tt] + threadIdx.x;
    int i = slot - offs[e];
    int n = counts[e];
    idxc[slot] = (i < n) ? idxcap[e * T_TOK + i] : 0;
}

// ============ GEMM template ============
// LDS tile [128][64] bf16, single-buffered, two barriers/iter (m97 structure).
// XOR swizzle: LDS slot s of row r holds global k-slot s^(r&7); global source
// pre-swizzled so global_load_lds dest stays linear (both-sides swizzle).

// ---------------- GEMM1: h[slot] = gelu(x[tok] @ w1[e] + b1[e]) ----------------
__global__ __launch_bounds__(256, 2)
void gemm1_kernel(const __hip_bfloat16* __restrict__ xb,    // [T][H]
                  const __hip_bfloat16* __restrict__ w1b,   // [E][INTER][H]  (K-major)
                  const float* __restrict__ b1,             // [E][INTER]
                  const int* __restrict__ idxc,
                  const int* __restrict__ tile_e, const int* __restrict__ tile_s0,
                  const int* __restrict__ ntiles,
                  __hip_bfloat16* __restrict__ h)           // [MAXSLOT][INTER]
{
    const int NWG = MAXT * (INTER / 128);                   // 2304, %8==0
    int bid = blockIdx.x;
    int w = (bid & 7) * (NWG / 8) + (bid >> 3);             // XCD-chunked
    int tt = w >> 5;                                        // n0-fast
    int n0 = (w & 31) * 128;
    if (tt >= *ntiles) return;
    int e = tile_e[tt];
    int slot0 = tile_s0[tt];

    __shared__ __hip_bfloat16 As[128][64];
    __shared__ __hip_bfloat16 Bs[128][64];
    __shared__ int s_idx[128];

    int tid = threadIdx.x, wv = tid >> 6, ln = tid & 63;
    if (tid < 128) s_idx[tid] = idxc[slot0 + tid];
    __syncthreads();

    int swz = ((ln & 7) ^ (ln >> 3)) * 8;                   // pre-swizzled k-offset (elems)
    const __hip_bfloat16* srcA[4];
    const __hip_bfloat16* srcB[4];
    const __hip_bfloat16* wbase = w1b + (size_t)e * INTER * HID;
    #pragma unroll
    for (int j = 0; j < 4; ++j) {
        int r = wv * 32 + j * 8 + (ln >> 3);
        srcA[j] = xb + (size_t)s_idx[r] * HID + swz;
        srcB[j] = wbase + (size_t)(n0 + r) * HID + swz;
    }

    f32x4 acc[4][4] = {};
    int wr = wv >> 1, wc = wv & 1, lr = ln & 15;

    for (int kt = 0; kt < HID; kt += 64) {
        #pragma unroll
        for (int j = 0; j < 4; ++j) {
            load_lds16(srcA[j] + kt, (void*)&As[wv * 32 + j * 8][0]);
            load_lds16(srcB[j] + kt, (void*)&Bs[wv * 32 + j * 8][0]);
        }
        __syncthreads();
        #pragma unroll
        for (int kk = 0; kk < 2; ++kk) {
            int lslot = (((kk * 4) + (ln >> 4)) ^ (ln & 7)) * 16;
            s16x8 af[4], bf[4];
            #pragma unroll
            for (int m = 0; m < 4; ++m) {
                int row = wr * 64 + m * 16 + lr;
                af[m] = *(const s16x8*)((const char*)&As[0][0] + row * 128 + lslot);
            }
            #pragma unroll
            for (int n = 0; n < 4; ++n) {
                int row = wc * 64 + n * 16 + lr;
                bf[n] = *(const s16x8*)((const char*)&Bs[0][0] + row * 128 + lslot);
            }
            #pragma unroll
            for (int m = 0; m < 4; ++m)
                #pragma unroll
                for (int n = 0; n < 4; ++n)
                    acc[m][n] = __builtin_amdgcn_mfma_f32_16x16x32_bf16(af[m], bf[n], acc[m][n], 0, 0, 0);
        }
        __syncthreads();
    }

    const float* b1e = b1 + (size_t)e * INTER;
    int rq = (ln >> 4) * 4;
    #pragma unroll
    for (int m = 0; m < 4; ++m) {
        #pragma unroll
        for (int r = 0; r < 4; ++r) {
            int row = wr * 64 + m * 16 + rq + r;
            size_t hrow = (size_t)(slot0 + row) * INTER;
            #pragma unroll
            for (int n = 0; n < 4; ++n) {
                int col = n0 + wc * 64 + n * 16 + lr;
                float v = acc[m][n][r] + b1e[col];
                h[hrow + col] = __float2bfloat16(gelu_tanh(v));
            }
        }
    }
}

// ---------------- GEMM2 (split-K=2): out[tok] += g * (h[slot] @ w2[e] + b2[e]) ----------------
__global__ __launch_bounds__(256, 2)
void gemm2_kernel(const __hip_bfloat16* __restrict__ h,     // [MAXSLOT][INTER]
                  const __hip_bfloat16* __restrict__ w2b,   // [E][H][INTER]  (K-major)
                  const float* __restrict__ b2,             // [E][H]
                  const float* __restrict__ combine,        // [T][E]
                  const int* __restrict__ idxc,
                  const int* __restrict__ tile_e, const int* __restrict__ tile_s0,
                  const int* __restrict__ tile_nv, const int* __restrict__ ntiles,
                  float* __restrict__ out)                  // [T][H]
{
    const int NWG = MAXT * (HID / 128) * 2;                 // 1152, %8==0
    int bid = blockIdx.x;
    int w = (bid & 7) * (NWG / 8) + (bid >> 3);             // XCD-chunked
    int ks = w & 1;                                         // split-K half
    int n0 = ((w >> 1) & 7) * 128;
    int tt = w >> 4;
    if (tt >= *ntiles) return;
    int e = tile_e[tt];
    int slot0 = tile_s0[tt];

    __shared__ __hip_bfloat16 As[128][64];
    __shared__ __hip_bfloat16 Bs[128][64];
    __shared__ int s_idx[128];

    int tid = threadIdx.x, wv = tid >> 6, ln = tid & 63;
    if (tid < 128) s_idx[tid] = idxc[slot0 + tid];

    int swz = ((ln & 7) ^ (ln >> 3)) * 8;
    const __hip_bfloat16* srcA[4];
    const __hip_bfloat16* srcB[4];
    const __hip_bfloat16* wbase = w2b + (size_t)e * HID * INTER;
    #pragma unroll
    for (int j = 0; j < 4; ++j) {
        int r = wv * 32 + j * 8 + (ln >> 3);
        srcA[j] = h + (size_t)(slot0 + r) * INTER + swz;
        srcB[j] = wbase + (size_t)(n0 + r) * INTER + swz;
    }

    f32x4 acc[4][4] = {};
    int wr = wv >> 1, wc = wv & 1, lr = ln & 15;

    int k0 = ks * (INTER / 2), k1 = k0 + INTER / 2;
    for (int kt = k0; kt < k1; kt += 64) {
        #pragma unroll
        for (int j = 0; j < 4; ++j) {
            load_lds16(srcA[j] + kt, (void*)&As[wv * 32 + j * 8][0]);
            load_lds16(srcB[j] + kt, (void*)&Bs[wv * 32 + j * 8][0]);
        }
        __syncthreads();
        #pragma unroll
        for (int kk = 0; kk < 2; ++kk) {
            int lslot = (((kk * 4) + (ln >> 4)) ^ (ln & 7)) * 16;
            s16x8 af[4], bf[4];
            #pragma unroll
            for (int m = 0; m < 4; ++m) {
                int row = wr * 64 + m * 16 + lr;
                af[m] = *(const s16x8*)((const char*)&As[0][0] + row * 128 + lslot);
            }
            #pragma unroll
            for (int n = 0; n < 4; ++n) {
                int row = wc * 64 + n * 16 + lr;
                bf[n] = *(const s16x8*)((const char*)&Bs[0][0] + row * 128 + lslot);
            }
            #pragma unroll
            for (int m = 0; m < 4; ++m)
                #pragma unroll
                for (int n = 0; n < 4; ++n)
                    acc[m][n] = __builtin_amdgcn_mfma_f32_16x16x32_bf16(af[m], bf[n], acc[m][n], 0, 0, 0);
        }
        __syncthreads();
    }

    const float* b2e = b2 + (size_t)e * HID;
    int nv = tile_nv[tt];
    int rq = (ln >> 4) * 4;
    #pragma unroll
    for (int m = 0; m < 4; ++m) {
        #pragma unroll
        for (int r = 0; r < 4; ++r) {
            int row = wr * 64 + m * 16 + rq + r;
            if (row < nv) {
                int tok = s_idx[row];
                float g = combine[(size_t)tok * 8 + e];
                #pragma unroll
                for (int n = 0; n < 4; ++n) {
                    int col = n0 + wc * 64 + n * 16 + lr;
                    float v = acc[m][n][r] + (ks == 0 ? b2e[col] : 0.f);
                    atomicAdd(&out[(size_t)tok * HID + col], g * v);
                }
            }
        }
    }
}

// ---------------- workspace layout ----------------
static const size_t OFF_XB      = 0;
static const size_t SZ_XB       = (size_t)T_TOK * HID * 2;
static const size_t OFF_W1B     = OFF_XB + SZ_XB;
static const size_t SZ_W        = (size_t)NEXP * INTER * HID * 2;
static const size_t OFF_W2B     = OFF_W1B + SZ_W;
static const size_t OFF_H       = OFF_W2B + SZ_W;
static const size_t SZ_H        = (size_t)MAXSLOT * INTER * 2;
static const size_t OFF_COMBINE = OFF_H + SZ_H;
static const size_t OFF_IDXCAP  = OFF_COMBINE + (size_t)T_TOK * 8 * 4;
static const size_t OFF_IDXC    = OFF_IDXCAP + (size_t)NEXP * T_TOK * 4;
static const size_t OFF_COUNTS  = OFF_IDXC + (size_t)MAXSLOT * 4;   // 8 ints
static const size_t OFF_PSUMS   = OFF_COUNTS + 32;                  // 8 floats
static const size_t OFF_OFFS    = OFF_PSUMS + 32;                   // 8 ints
static const size_t OFF_TILE_E  = OFF_OFFS + 64;
static const size_t OFF_TILE_S0 = OFF_TILE_E + 512;
static const size_t OFF_TILE_NV = OFF_TILE_S0 + 512;
static const size_t OFF_NTILES  = OFF_TILE_NV + 512;

extern "C" void kernel_launch(void* const* d_in, const int* in_sizes, int n_in,
                              void* d_out, int out_size, void* d_ws, size_t ws_size,
                              hipStream_t stream) {
    const float* x  = (const float*)d_in[0];
    const float* Wg = (const float*)d_in[1];
    const float* w1 = (const float*)d_in[2];
    const float* b1 = (const float*)d_in[3];
    const float* w2 = (const float*)d_in[4];
    const float* b2 = (const float*)d_in[5];
    float* out = (float*)d_out;
    char* ws = (char*)d_ws;

    __hip_bfloat16* xb   = (__hip_bfloat16*)(ws + OFF_XB);
    __hip_bfloat16* w1b  = (__hip_bfloat16*)(ws + OFF_W1B);
    __hip_bfloat16* w2b  = (__hip_bfloat16*)(ws + OFF_W2B);
    __hip_bfloat16* h    = (__hip_bfloat16*)(ws + OFF_H);
    float* combine       = (float*)(ws + OFF_COMBINE);
    int*   idxcap        = (int*)(ws + OFF_IDXCAP);
    int*   idxc          = (int*)(ws + OFF_IDXC);
    int*   counts        = (int*)(ws + OFF_COUNTS);
    float* psums         = (float*)(ws + OFF_PSUMS);
    int*   offs          = (int*)(ws + OFF_OFFS);
    int*   tile_e        = (int*)(ws + OFF_TILE_E);
    int*   tile_s0       = (int*)(ws + OFF_TILE_S0);
    int*   tile_nv       = (int*)(ws + OFF_TILE_NV);
    int*   ntiles        = (int*)(ws + OFF_NTILES);

    (void)hipMemsetAsync(out, 0, (size_t)out_size * sizeof(float), stream);
    (void)hipMemsetAsync(ws + OFF_COUNTS, 0, 64, stream);

    transpose_bf16_kernel<<<dim3(INTER / 32, HID / 32, NEXP), 256, 0, stream>>>(w1, w1b, HID, INTER);
    transpose_bf16_kernel<<<dim3(HID / 32, INTER / 32, NEXP), 256, 0, stream>>>(w2, w2b, INTER, HID);
    gating_kernel<<<T_TOK / TPB_TOK, 256, 0, stream>>>(x, Wg, xb, combine, counts, psums, idxcap);
    plan_kernel<<<1, 1, 0, stream>>>(counts, psums, offs, tile_e, tile_s0, tile_nv, ntiles,
                                     out + (size_t)T_TOK * HID);
    compact_kernel<<<MAXT, 128, 0, stream>>>(counts, offs, tile_e, tile_s0, ntiles, idxcap, idxc);
    gemm1_kernel<<<MAXT * (INTER / 128), 256, 0, stream>>>(xb, w1b, b1, idxc, tile_e, tile_s0,
                                                           ntiles, h);
    gemm2_kernel<<<MAXT * (HID / 128) * 2, 256, 0, stream>>>(h, w2b, b2, combine, idxc, tile_e,
                                                             tile_s0, tile_nv, ntiles, out);
}

// Round 6
// 370.204 us; speedup vs baseline: 1.2489x; 1.0341x over previous
//
#include <hip/hip_runtime.h>
#include <hip/hip_bf16.h>

// ---------------- constants ----------------
#define T_TOK   4096
#define HID     1024
#define INTER   4096
#define NEXP    8
#define MAXT    72          // max total row-tiles: (8192 + 8*127)/128 = 72
#define MAXSLOT 9216        // MAXT * 128
#define TPB_TOK 16          // tokens per gating block

typedef __attribute__((ext_vector_type(8))) short s16x8;
typedef __attribute__((ext_vector_type(4))) float f32x4;

__device__ __forceinline__ void load_lds16(const void* g, void* l) {
    __builtin_amdgcn_global_load_lds(
        (const __attribute__((address_space(1))) void*)g,
        (__attribute__((address_space(3))) void*)l, 16, 0, 0);
}

// gelu(tanh approx) = v * sigmoid(2*z), z = c*(v + 0.044715 v^3)
__device__ __forceinline__ float gelu_tanh(float v) {
    float c = 0.7978845608028654f;
    float z = c * (v + 0.044715f * v * v * v);
    return v / (1.0f + __expf(-2.0f * z));
}

// ---------------- transpose+convert weights: in [E][R][C] f32 -> out [E][C][R] bf16 ----------------
// 64x64 tiles, float4 loads, short8 stores
__global__ void transpose_bf16_kernel(const float* __restrict__ in, __hip_bfloat16* __restrict__ out,
                                      int R, int C) {
    __shared__ float tile[64][65];
    size_t eoff = (size_t)blockIdx.z * R * C;
    int c0 = blockIdx.x * 64, r0 = blockIdx.y * 64;
    int tid = threadIdx.x;

    int lr = tid >> 4;            // 0..15
    int lc = (tid & 15) * 4;
    #pragma unroll
    for (int it = 0; it < 4; ++it) {
        int r = it * 16 + lr;
        float4 v = *(const float4*)(in + eoff + (size_t)(r0 + r) * C + c0 + lc);
        tile[r][lc + 0] = v.x; tile[r][lc + 1] = v.y;
        tile[r][lc + 2] = v.z; tile[r][lc + 3] = v.w;
    }
    __syncthreads();

    int oc = tid >> 3;            // 0..31
    int r8 = (tid & 7) * 8;
    #pragma unroll
    for (int it = 0; it < 2; ++it) {
        int c = it * 32 + oc;
        alignas(16) __hip_bfloat16 o[8];
        #pragma unroll
        for (int j = 0; j < 8; ++j) o[j] = __float2bfloat16(tile[r8 + j][c]);
        *(s16x8*)(out + eoff + (size_t)(c0 + c) * R + r0 + r8) = *(const s16x8*)o;
    }
}

// ---------------- gating: 16 tokens per block, block-aggregated atomics ----------------
__global__ void gating_kernel(const float* __restrict__ x, const float* __restrict__ Wg,
                              __hip_bfloat16* __restrict__ xb,
                              float* __restrict__ combine, int* __restrict__ counts,
                              float* __restrict__ prob_sums, int* __restrict__ idxcap) {
    __shared__ float s_ps[NEXP];
    __shared__ int   s_cnt[NEXP];
    __shared__ int   s_base[NEXP];
    __shared__ int   s_ei[TPB_TOK][2];
    __shared__ int   s_rk[TPB_TOK][2];

    int tid = threadIdx.x, wv = tid >> 6, ln = tid & 63;
    if (tid < NEXP) { s_ps[tid] = 0.f; s_cnt[tid] = 0; }
    __syncthreads();

    int t0 = blockIdx.x * TPB_TOK;
    for (int sub = 0; sub < 4; ++sub) {
        int tl = wv * 4 + sub;          // 0..15 local token
        int t = t0 + tl;
        const float* xr = x + (size_t)t * HID + ln * 16;
        float4 xv[4];
        #pragma unroll
        for (int i = 0; i < 4; ++i) xv[i] = *(const float4*)(xr + i * 4);

        alignas(16) __hip_bfloat16 row[16];
        #pragma unroll
        for (int i = 0; i < 4; ++i) {
            row[i * 4 + 0] = __float2bfloat16(xv[i].x);
            row[i * 4 + 1] = __float2bfloat16(xv[i].y);
            row[i * 4 + 2] = __float2bfloat16(xv[i].z);
            row[i * 4 + 3] = __float2bfloat16(xv[i].w);
        }
        __hip_bfloat16* xbr = xb + (size_t)t * HID + ln * 16;
        *(s16x8*)(xbr)     = *(s16x8*)&row[0];
        *(s16x8*)(xbr + 8) = *(s16x8*)&row[8];

        float acc[NEXP] = {0,0,0,0,0,0,0,0};
        #pragma unroll
        for (int i = 0; i < 4; ++i) {
            float xs[4] = {xv[i].x, xv[i].y, xv[i].z, xv[i].w};
            #pragma unroll
            for (int j = 0; j < 4; ++j) {
                int k = ln * 16 + i * 4 + j;
                float4 wa = *(const float4*)(Wg + (size_t)k * 8);
                float4 wb = *(const float4*)(Wg + (size_t)k * 8 + 4);
                acc[0] += xs[j] * wa.x; acc[1] += xs[j] * wa.y;
                acc[2] += xs[j] * wa.z; acc[3] += xs[j] * wa.w;
                acc[4] += xs[j] * wb.x; acc[5] += xs[j] * wb.y;
                acc[6] += xs[j] * wb.z; acc[7] += xs[j] * wb.w;
            }
        }
        #pragma unroll
        for (int e = 0; e < NEXP; ++e)
            #pragma unroll
            for (int off = 32; off >= 1; off >>= 1)
                acc[e] += __shfl_xor(acc[e], off);

        float m = acc[0];
        #pragma unroll
        for (int e = 1; e < NEXP; ++e) m = fmaxf(m, acc[e]);
        float p[NEXP], s = 0.f;
        #pragma unroll
        for (int e = 0; e < NEXP; ++e) { p[e] = __expf(acc[e] - m); s += p[e]; }
        float inv = 1.0f / s;
        #pragma unroll
        for (int e = 0; e < NEXP; ++e) p[e] *= inv;

        int i0 = 0;
        #pragma unroll
        for (int e = 1; e < NEXP; ++e) if (p[e] > p[i0]) i0 = e;
        int i1 = (i0 == 0) ? 1 : 0;
        #pragma unroll
        for (int e = 0; e < NEXP; ++e) if (e != i0 && p[e] > p[i1]) i1 = e;
        float gs = p[i0] + p[i1];
        float g0 = p[i0] / gs, g1 = p[i1] / gs;

        if (ln == 0) {
            float rowc[NEXP] = {0,0,0,0,0,0,0,0};
            rowc[i0] = g0; rowc[i1] = g1;
            float4* cr = (float4*)(combine + (size_t)t * NEXP);
            cr[0] = make_float4(rowc[0], rowc[1], rowc[2], rowc[3]);
            cr[1] = make_float4(rowc[4], rowc[5], rowc[6], rowc[7]);
            #pragma unroll
            for (int e = 0; e < NEXP; ++e) atomicAdd(&s_ps[e], p[e]);
            int r0 = atomicAdd(&s_cnt[i0], 1);
            int r1 = atomicAdd(&s_cnt[i1], 1);
            s_ei[tl][0] = i0; s_rk[tl][0] = r0;
            s_ei[tl][1] = i1; s_rk[tl][1] = r1;
        }
    }
    __syncthreads();
    if (tid < NEXP) {
        s_base[tid] = atomicAdd(&counts[tid], s_cnt[tid]);
        atomicAdd(&prob_sums[tid], s_ps[tid]);
    }
    __syncthreads();
    if (tid < TPB_TOK * 2) {
        int tl = tid >> 1, k = tid & 1;
        int e = s_ei[tl][k];
        idxcap[e * T_TOK + s_base[e] + s_rk[tl][k]] = t0 + tl;
    }
}

// ---------------- plan: offsets, tile table, aux loss (1 thread) ----------------
__global__ void plan_kernel(const int* __restrict__ counts, const float* __restrict__ prob_sums,
                            int* __restrict__ offs, int* __restrict__ tile_e,
                            int* __restrict__ tile_s0, int* __restrict__ tile_nv,
                            int* __restrict__ ntiles, float* __restrict__ aux_out) {
    int tt = 0, o = 0;
    for (int e = 0; e < NEXP; ++e) {
        offs[e] = o;
        int n = counts[e];
        int nt = (n + 127) >> 7;
        for (int r = 0; r < nt; ++r) {
            tile_e[tt] = e;
            tile_s0[tt] = o + r * 128;
            int nv = n - r * 128; if (nv > 128) nv = 128;
            tile_nv[tt] = nv;
            ++tt;
        }
        o += nt * 128;
    }
    *ntiles = tt;
    float aux = 0.f;
    for (int e = 0; e < NEXP; ++e)
        aux += ((float)counts[e] / (float)(T_TOK * 2)) * (prob_sums[e] / (float)T_TOK);
    aux_out[0] = (float)NEXP * aux * 0.01f;
}

// ---------------- compact token list ----------------
__global__ void compact_kernel(const int* __restrict__ counts, const int* __restrict__ offs,
                               const int* __restrict__ tile_e, const int* __restrict__ tile_s0,
                               const int* __restrict__ ntiles,
                               const int* __restrict__ idxcap, int* __restrict__ idxc) {
    int tt = blockIdx.x;
    if (tt >= *ntiles) return;
    int e = tile_e[tt];
    int slot = tile_s0[tt] + threadIdx.x;
    int i = slot - offs[e];
    int n = counts[e];
    idxc[slot] = (i < n) ? idxcap[e * T_TOK + i] : 0;
}

// ============ GEMM template ============
// LDS tile [128][64] bf16, single-buffered, two barriers/iter (m97 structure).
// XOR swizzle: LDS slot s of row r holds global k-slot s^(r&7); global source
// pre-swizzled so global_load_lds dest stays linear (both-sides swizzle).

// ---------------- GEMM1: h[slot] = gelu(x[tok] @ w1[e] + b1[e]) ----------------
__global__ __launch_bounds__(256, 3)
void gemm1_kernel(const __hip_bfloat16* __restrict__ xb,    // [T][H]
                  const __hip_bfloat16* __restrict__ w1b,   // [E][INTER][H]  (K-major)
                  const float* __restrict__ b1,             // [E][INTER]
                  const int* __restrict__ idxc,
                  const int* __restrict__ tile_e, const int* __restrict__ tile_s0,
                  const int* __restrict__ ntiles,
                  __hip_bfloat16* __restrict__ h)           // [MAXSLOT][INTER]
{
    const int NWG = MAXT * (INTER / 128);                   // 2304, %8==0
    int bid = blockIdx.x;
    int w = (bid & 7) * (NWG / 8) + (bid >> 3);             // XCD-chunked
    int tt = w >> 5;                                        // n0-fast
    int n0 = (w & 31) * 128;
    if (tt >= *ntiles) return;
    int e = tile_e[tt];
    int slot0 = tile_s0[tt];

    __shared__ __hip_bfloat16 As[128][64];
    __shared__ __hip_bfloat16 Bs[128][64];
    __shared__ int s_idx[128];

    int tid = threadIdx.x, wv = tid >> 6, ln = tid & 63;
    if (tid < 128) s_idx[tid] = idxc[slot0 + tid];
    __syncthreads();

    int swz = ((ln & 7) ^ (ln >> 3)) * 8;                   // pre-swizzled k-offset (elems)
    const __hip_bfloat16* srcA[4];
    const __hip_bfloat16* srcB[4];
    const __hip_bfloat16* wbase = w1b + (size_t)e * INTER * HID;
    #pragma unroll
    for (int j = 0; j < 4; ++j) {
        int r = wv * 32 + j * 8 + (ln >> 3);
        srcA[j] = xb + (size_t)s_idx[r] * HID + swz;
        srcB[j] = wbase + (size_t)(n0 + r) * HID + swz;
    }

    f32x4 acc[4][4] = {};
    int wr = wv >> 1, wc = wv & 1, lr = ln & 15;

    for (int kt = 0; kt < HID; kt += 64) {
        #pragma unroll
        for (int j = 0; j < 4; ++j) {
            load_lds16(srcA[j] + kt, (void*)&As[wv * 32 + j * 8][0]);
            load_lds16(srcB[j] + kt, (void*)&Bs[wv * 32 + j * 8][0]);
        }
        __syncthreads();
        #pragma unroll
        for (int kk = 0; kk < 2; ++kk) {
            int lslot = (((kk * 4) + (ln >> 4)) ^ (ln & 7)) * 16;
            s16x8 af[4], bf[4];
            #pragma unroll
            for (int m = 0; m < 4; ++m) {
                int row = wr * 64 + m * 16 + lr;
                af[m] = *(const s16x8*)((const char*)&As[0][0] + row * 128 + lslot);
            }
            #pragma unroll
            for (int n = 0; n < 4; ++n) {
                int row = wc * 64 + n * 16 + lr;
                bf[n] = *(const s16x8*)((const char*)&Bs[0][0] + row * 128 + lslot);
            }
            #pragma unroll
            for (int m = 0; m < 4; ++m)
                #pragma unroll
                for (int n = 0; n < 4; ++n)
                    acc[m][n] = __builtin_amdgcn_mfma_f32_16x16x32_bf16(af[m], bf[n], acc[m][n], 0, 0, 0);
        }
        __syncthreads();
    }

    const float* b1e = b1 + (size_t)e * INTER;
    int rq = (ln >> 4) * 4;
    #pragma unroll
    for (int m = 0; m < 4; ++m) {
        #pragma unroll
        for (int r = 0; r < 4; ++r) {
            int row = wr * 64 + m * 16 + rq + r;
            size_t hrow = (size_t)(slot0 + row) * INTER;
            #pragma unroll
            for (int n = 0; n < 4; ++n) {
                int col = n0 + wc * 64 + n * 16 + lr;
                float v = acc[m][n][r] + b1e[col];
                h[hrow + col] = __float2bfloat16(gelu_tanh(v));
            }
        }
    }
}

// ---------------- GEMM2 (split-K=2): out[tok] += g * (h[slot] @ w2[e] + b2[e]) ----------------
__global__ __launch_bounds__(256, 3)
void gemm2_kernel(const __hip_bfloat16* __restrict__ h,     // [MAXSLOT][INTER]
                  const __hip_bfloat16* __restrict__ w2b,   // [E][H][INTER]  (K-major)
                  const float* __restrict__ b2,             // [E][H]
                  const float* __restrict__ combine,        // [T][E]
                  const int* __restrict__ idxc,
                  const int* __restrict__ tile_e, const int* __restrict__ tile_s0,
                  const int* __restrict__ tile_nv, const int* __restrict__ ntiles,
                  float* __restrict__ out)                  // [T][H]
{
    const int NWG = MAXT * (HID / 128) * 2;                 // 1152, %8==0
    int bid = blockIdx.x;
    int w = (bid & 7) * (NWG / 8) + (bid >> 3);             // XCD-chunked
    int ks = w & 1;                                         // split-K half
    int n0 = ((w >> 1) & 7) * 128;
    int tt = w >> 4;
    if (tt >= *ntiles) return;
    int e = tile_e[tt];
    int slot0 = tile_s0[tt];

    __shared__ __hip_bfloat16 As[128][64];
    __shared__ __hip_bfloat16 Bs[128][64];
    __shared__ int s_idx[128];

    int tid = threadIdx.x, wv = tid >> 6, ln = tid & 63;
    if (tid < 128) s_idx[tid] = idxc[slot0 + tid];
    __syncthreads();

    int swz = ((ln & 7) ^ (ln >> 3)) * 8;
    const __hip_bfloat16* srcA[4];
    const __hip_bfloat16* srcB[4];
    const __hip_bfloat16* wbase = w2b + (size_t)e * HID * INTER;
    #pragma unroll
    for (int j = 0; j < 4; ++j) {
        int r = wv * 32 + j * 8 + (ln >> 3);
        srcA[j] = h + (size_t)(slot0 + r) * INTER + swz;
        srcB[j] = wbase + (size_t)(n0 + r) * INTER + swz;
    }

    f32x4 acc[4][4] = {};
    int wr = wv >> 1, wc = wv & 1, lr = ln & 15;

    int k0 = ks * (INTER / 2), k1 = k0 + INTER / 2;
    for (int kt = k0; kt < k1; kt += 64) {
        #pragma unroll
        for (int j = 0; j < 4; ++j) {
            load_lds16(srcA[j] + kt, (void*)&As[wv * 32 + j * 8][0]);
            load_lds16(srcB[j] + kt, (void*)&Bs[wv * 32 + j * 8][0]);
        }
        __syncthreads();
        #pragma unroll
        for (int kk = 0; kk < 2; ++kk) {
            int lslot = (((kk * 4) + (ln >> 4)) ^ (ln & 7)) * 16;
            s16x8 af[4], bf[4];
            #pragma unroll
            for (int m = 0; m < 4; ++m) {
                int row = wr * 64 + m * 16 + lr;
                af[m] = *(const s16x8*)((const char*)&As[0][0] + row * 128 + lslot);
            }
            #pragma unroll
            for (int n = 0; n < 4; ++n) {
                int row = wc * 64 + n * 16 + lr;
                bf[n] = *(const s16x8*)((const char*)&Bs[0][0] + row * 128 + lslot);
            }
            #pragma unroll
            for (int m = 0; m < 4; ++m)
                #pragma unroll
                for (int n = 0; n < 4; ++n)
                    acc[m][n] = __builtin_amdgcn_mfma_f32_16x16x32_bf16(af[m], bf[n], acc[m][n], 0, 0, 0);
        }
        __syncthreads();
    }

    const float* b2e = b2 + (size_t)e * HID;
    int nv = tile_nv[tt];
    int rq = (ln >> 4) * 4;
    #pragma unroll
    for (int m = 0; m < 4; ++m) {
        #pragma unroll
        for (int r = 0; r < 4; ++r) {
            int row = wr * 64 + m * 16 + rq + r;
            if (row < nv) {
                int tok = s_idx[row];
                float g = combine[(size_t)tok * 8 + e];
                #pragma unroll
                for (int n = 0; n < 4; ++n) {
                    int col = n0 + wc * 64 + n * 16 + lr;
                    float v = acc[m][n][r] + (ks == 0 ? b2e[col] : 0.f);
                    atomicAdd(&out[(size_t)tok * HID + col], g * v);
                }
            }
        }
    }
}

// ---------------- workspace layout ----------------
static const size_t OFF_XB      = 0;
static const size_t SZ_XB       = (size_t)T_TOK * HID * 2;
static const size_t OFF_W1B     = OFF_XB + SZ_XB;
static const size_t SZ_W        = (size_t)NEXP * INTER * HID * 2;
static const size_t OFF_W2B     = OFF_W1B + SZ_W;
static const size_t OFF_H       = OFF_W2B + SZ_W;
static const size_t SZ_H        = (size_t)MAXSLOT * INTER * 2;
static const size_t OFF_COMBINE = OFF_H + SZ_H;
static const size_t OFF_IDXCAP  = OFF_COMBINE + (size_t)T_TOK * 8 * 4;
static const size_t OFF_IDXC    = OFF_IDXCAP + (size_t)NEXP * T_TOK * 4;
static const size_t OFF_COUNTS  = OFF_IDXC + (size_t)MAXSLOT * 4;   // 8 ints
static const size_t OFF_PSUMS   = OFF_COUNTS + 32;                  // 8 floats
static const size_t OFF_OFFS    = OFF_PSUMS + 32;                   // 8 ints
static const size_t OFF_TILE_E  = OFF_OFFS + 64;
static const size_t OFF_TILE_S0 = OFF_TILE_E + 512;
static const size_t OFF_TILE_NV = OFF_TILE_S0 + 512;
static const size_t OFF_NTILES  = OFF_TILE_NV + 512;

extern "C" void kernel_launch(void* const* d_in, const int* in_sizes, int n_in,
                              void* d_out, int out_size, void* d_ws, size_t ws_size,
                              hipStream_t stream) {
    const float* x  = (const float*)d_in[0];
    const float* Wg = (const float*)d_in[1];
    const float* w1 = (const float*)d_in[2];
    const float* b1 = (const float*)d_in[3];
    const float* w2 = (const float*)d_in[4];
    const float* b2 = (const float*)d_in[5];
    float* out = (float*)d_out;
    char* ws = (char*)d_ws;

    __hip_bfloat16* xb   = (__hip_bfloat16*)(ws + OFF_XB);
    __hip_bfloat16* w1b  = (__hip_bfloat16*)(ws + OFF_W1B);
    __hip_bfloat16* w2b  = (__hip_bfloat16*)(ws + OFF_W2B);
    __hip_bfloat16* h    = (__hip_bfloat16*)(ws + OFF_H);
    float* combine       = (float*)(ws + OFF_COMBINE);
    int*   idxcap        = (int*)(ws + OFF_IDXCAP);
    int*   idxc          = (int*)(ws + OFF_IDXC);
    int*   counts        = (int*)(ws + OFF_COUNTS);
    float* psums         = (float*)(ws + OFF_PSUMS);
    int*   offs          = (int*)(ws + OFF_OFFS);
    int*   tile_e        = (int*)(ws + OFF_TILE_E);
    int*   tile_s0       = (int*)(ws + OFF_TILE_S0);
    int*   tile_nv       = (int*)(ws + OFF_TILE_NV);
    int*   ntiles        = (int*)(ws + OFF_NTILES);

    (void)hipMemsetAsync(out, 0, (size_t)out_size * sizeof(float), stream);
    (void)hipMemsetAsync(ws + OFF_COUNTS, 0, 64, stream);

    transpose_bf16_kernel<<<dim3(INTER / 64, HID / 64, NEXP), 256, 0, stream>>>(w1, w1b, HID, INTER);
    transpose_bf16_kernel<<<dim3(HID / 64, INTER / 64, NEXP), 256, 0, stream>>>(w2, w2b, INTER, HID);
    gating_kernel<<<T_TOK / TPB_TOK, 256, 0, stream>>>(x, Wg, xb, combine, counts, psums, idxcap);
    plan_kernel<<<1, 1, 0, stream>>>(counts, psums, offs, tile_e, tile_s0, tile_nv, ntiles,
                                     out + (size_t)T_TOK * HID);
    compact_kernel<<<MAXT, 128, 0, stream>>>(counts, offs, tile_e, tile_s0, ntiles, idxcap, idxc);
    gemm1_kernel<<<MAXT * (INTER / 128), 256, 0, stream>>>(xb, w1b, b1, idxc, tile_e, tile_s0,
                                                           ntiles, h);
    gemm2_kernel<<<MAXT * (HID / 128) * 2, 256, 0, stream>>>(h, w2b, b2, combine, idxc, tile_e,
                                                             tile_s0, tile_nv, ntiles, out);
}